// Round 8
// baseline (318.184 us; speedup 1.0000x reference)
//
#include <hip/hip_runtime.h>
#include <math.h>

// MHA forward: B=4, S=2048, E=1024, H=16, D=64. bf16 MFMA path.
// Round 12: attn_fwd rewritten on 32x32 MFMA tiles (m214-style swapped-QK):
//  - S^T = mfma32(K,Q): lane owns q-column c31; softmax = 15 fmax + 1 shfl.
//  - O^T = mfma32(V^T, P): P B-frag built IN REGISTER from own packs +
//    partner packs via ds_bpermute(lane^32) — the Pb LDS transpose buffer
//    (18.4KB + its bank conflicts, constant 3.24M cyc/dispatch) is deleted.
//  - LDS 51200 -> 32768 B: grid 1024 = 4 blocks/CU single phase (cap 5).
//  - 16x mfma_32x32x16 per 32q x 64k iter = 128cy vs 160cy at 16x16 (-20%).
//  - rescale/epilogue lane-local (O^T col = q = lane): no shfl needed.
// K/V GLDS16 double-buffer staging, LPT stripe order, defer-max, setprio
// all carried over. gemm/cvt kernels unchanged from round 11.

#define EMBED 1024
#define SEQ   2048
#define NH    16
#define HD    64
#define QSCALE 0.18033688011112042f   // 0.125 * log2(e), folded into Q proj

typedef __attribute__((ext_vector_type(4))) float f32x4;
typedef __attribute__((ext_vector_type(16))) float f32x16;
typedef __attribute__((ext_vector_type(8))) short s16x8;
typedef __attribute__((ext_vector_type(4))) short s16x4;
typedef __attribute__((ext_vector_type(4))) unsigned int u32x4;
typedef __attribute__((ext_vector_type(2))) unsigned int u32x2;

#define GLDS16(gp, lp) __builtin_amdgcn_global_load_lds( \
    (const __attribute__((address_space(1))) void*)(gp), \
    (__attribute__((address_space(3))) void*)(lp), 16, 0, 0)

__device__ __forceinline__ unsigned short f2bf(float f) {   // RNE
    unsigned int u = __builtin_bit_cast(unsigned int, f);
    u += 0x7fffu + ((u >> 16) & 1u);
    return (unsigned short)(u >> 16);
}
// pack two fp32 -> bf16x2 dword by truncation (1 v_perm_b32)
__device__ __forceinline__ unsigned int pkbf(float lo, float hi) {
    return __builtin_amdgcn_perm(__builtin_bit_cast(unsigned int, hi),
                                 __builtin_bit_cast(unsigned int, lo),
                                 0x07060302u);
}

// ---------- fp32 -> bf16 (RNE): 4 weight tensors + 3 activation tensors ----
struct CvtArgs { const float* s[7]; unsigned short* d[7]; int n4[7]; };
__global__ void cvt_all(CvtArgs ca)
{
    const int t = blockIdx.y;
    const float* in = ca.s[t];
    unsigned short* out = ca.d[t];
    const int n4 = ca.n4[t];
    const int stride = gridDim.x * 256;
    for (int i = blockIdx.x * 256 + threadIdx.x; i < n4; i += stride) {
        f32x4 v = *(const f32x4*)(in + (size_t)i * 4);
        s16x4 p;
        p[0] = (short)f2bf(v[0]); p[1] = (short)f2bf(v[1]);
        p[2] = (short)f2bf(v[2]); p[3] = (short)f2bf(v[3]);
        *(s16x4*)(out + (size_t)i * 4) = p;
    }
}

// ---------------- QKV projection (z = 0:Q, 1:K, 2:V), pure bf16 ------------
struct ProjArgs {
    const unsigned short* X[3];
    const unsigned short* W[3];
    const float* Bz[3];
    unsigned short* Oz[3];
};
__global__ void __launch_bounds__(256, 4)
gemm_qkv(ProjArgs pa)
{
    __shared__ unsigned short Ab[128 * 64];    // bf16 X tile (16 KB), swizzled
    __shared__ unsigned short Bb[128 * 64];    // bf16 W tile (16 KB), swizzled
    const int z = blockIdx.z;
    const unsigned short* Xb = pa.X[z];
    const unsigned short* Wb = pa.W[z];
    const float* bias = pa.Bz[z];
    unsigned short* Out = pa.Oz[z];
    const float scale = (z == 0) ? QSCALE : 1.0f;
    const int tid = threadIdx.x, lane = tid & 63, wv = tid >> 6;
    const int g = lane >> 4, c = lane & 15;
    const int wx = wv & 1, wy = wv >> 1;
    const int bm0 = blockIdx.x * 128, bn0 = blockIdx.y * 128;

    f32x4 acc[4][4];
#pragma unroll
    for (int i = 0; i < 4; ++i)
#pragma unroll
        for (int n = 0; n < 4; ++n) acc[i][n] = f32x4{0.f, 0.f, 0.f, 0.f};

    for (int k0 = 0; k0 < EMBED; k0 += 64) {
        __syncthreads();
#pragma unroll
        for (int cc = 0; cc < 4; ++cc) {       // A bf16: 8 chunks/row, swz ^(row&7)
            int li = cc * 256 + tid;
            int row = li >> 3, ch = (li & 7) ^ (row & 7);
            GLDS16(Xb + (size_t)(bm0 + row) * EMBED + k0 + ch * 8,
                   Ab + cc * 2048 + wv * 512);
        }
#pragma unroll
        for (int cc = 0; cc < 4; ++cc) {       // B bf16: 8 chunks/row, swz ^(row&7)
            int li = cc * 256 + tid;
            int row = li >> 3, ch = (li & 7) ^ (row & 7);
            GLDS16(Wb + (size_t)(bn0 + row) * EMBED + k0 + ch * 8,
                   Bb + cc * 2048 + wv * 512);
        }
        __syncthreads();
#pragma unroll
        for (int ks = 0; ks < 2; ++ks) {
            const int ib = ((ks * 4 + g) ^ (c & 7)) * 8;
            s16x8 af[4], bfr[4];
#pragma unroll
            for (int i = 0; i < 4; ++i)
                af[i] = *(const s16x8*)(&Ab[(wy * 64 + i * 16 + c) * 64 + ib]);
#pragma unroll
            for (int n = 0; n < 4; ++n)
                bfr[n] = *(const s16x8*)(&Bb[(wx * 64 + n * 16 + c) * 64 + ib]);
#pragma unroll
            for (int i = 0; i < 4; ++i)
#pragma unroll
                for (int n = 0; n < 4; ++n)
                    acc[i][n] = __builtin_amdgcn_mfma_f32_16x16x32_bf16(af[i], bfr[n], acc[i][n], 0, 0, 0);
        }
    }
    if (z < 2) {        // Q/K -> [B][H][S][D]
#pragma unroll
        for (int i = 0; i < 4; ++i) {
            int m0 = bm0 + wy * 64 + i * 16 + g * 4;
            int bb = m0 >> 11, s0 = m0 & 2047;
#pragma unroll
            for (int n = 0; n < 4; ++n) {
                int ncol = bn0 + wx * 64 + n * 16 + c;
                float bv = bias[ncol];
                int hh = ncol >> 6, dd = ncol & 63;
                size_t base = (((size_t)bb * NH + hh) * SEQ + s0) * HD + dd;
#pragma unroll
                for (int r = 0; r < 4; ++r)
                    Out[base + (size_t)r * HD] = f2bf((acc[i][n][r] + bv) * scale);
            }
        }
    } else {            // V -> V^T [B][H][D][S], 8B stores
#pragma unroll
        for (int i = 0; i < 4; ++i) {
            int m0 = bm0 + wy * 64 + i * 16 + g * 4;
            int bb = m0 >> 11, s0 = m0 & 2047;
#pragma unroll
            for (int n = 0; n < 4; ++n) {
                int ncol = bn0 + wx * 64 + n * 16 + c;
                float bv = bias[ncol];
                int hh = ncol >> 6, dd = ncol & 63;
                s16x4 pk;
#pragma unroll
                for (int r = 0; r < 4; ++r) pk[r] = (short)f2bf(acc[i][n][r] + bv);
                *(s16x4*)(&Out[(((size_t)bb * NH + hh) * HD + dd) * SEQ + s0]) = pk;
            }
        }
    }
}

// ---------------- output projection -----------------------------------------
__global__ void __launch_bounds__(256, 4)
gemm_out(const unsigned short* __restrict__ Xb, const unsigned short* __restrict__ Wb,
         const float* __restrict__ bias, float* __restrict__ Out)
{
    __shared__ unsigned short Ab[128 * 64];
    __shared__ unsigned short Bb[128 * 64];
    const int tid = threadIdx.x;
    const int lane = tid & 63, wv = tid >> 6;
    const int g = lane >> 4, c = lane & 15;
    const int wx = wv & 1, wy = wv >> 1;
    const int bm0 = blockIdx.x * 128, bn0 = blockIdx.y * 128;

    f32x4 acc[4][4];
#pragma unroll
    for (int i = 0; i < 4; ++i)
#pragma unroll
        for (int n = 0; n < 4; ++n) acc[i][n] = f32x4{0.f, 0.f, 0.f, 0.f};

    for (int k0 = 0; k0 < EMBED; k0 += 64) {
        __syncthreads();
#pragma unroll
        for (int cc = 0; cc < 4; ++cc) {
            int li = cc * 256 + tid;
            int row = li >> 3, ch = (li & 7) ^ (row & 7);
            GLDS16(Xb + (size_t)(bm0 + row) * EMBED + k0 + ch * 8,
                   Ab + cc * 2048 + wv * 512);
        }
#pragma unroll
        for (int cc = 0; cc < 4; ++cc) {
            int li = cc * 256 + tid;
            int row = li >> 3, ch = (li & 7) ^ (row & 7);
            GLDS16(Wb + (size_t)(bn0 + row) * EMBED + k0 + ch * 8,
                   Bb + cc * 2048 + wv * 512);
        }
        __syncthreads();
#pragma unroll
        for (int ks = 0; ks < 2; ++ks) {
            const int ib = ((ks * 4 + g) ^ (c & 7)) * 8;
            s16x8 af[4], bfr[4];
#pragma unroll
            for (int i = 0; i < 4; ++i)
                af[i] = *(const s16x8*)(&Ab[(wy * 64 + i * 16 + c) * 64 + ib]);
#pragma unroll
            for (int n = 0; n < 4; ++n)
                bfr[n] = *(const s16x8*)(&Bb[(wx * 64 + n * 16 + c) * 64 + ib]);
#pragma unroll
            for (int i = 0; i < 4; ++i)
#pragma unroll
                for (int n = 0; n < 4; ++n)
                    acc[i][n] = __builtin_amdgcn_mfma_f32_16x16x32_bf16(af[i], bfr[n], acc[i][n], 0, 0, 0);
        }
    }
#pragma unroll
    for (int i = 0; i < 4; ++i) {
#pragma unroll
        for (int n = 0; n < 4; ++n) {
            int ncol = bn0 + wx * 64 + n * 16 + c;
            float bv = bias[ncol];
#pragma unroll
            for (int r = 0; r < 4; ++r) {
                int m = bm0 + wy * 64 + i * 16 + g * 4 + r;
                Out[(size_t)m * EMBED + ncol] = acc[i][n][r] + bv;
            }
        }
    }
}

// ---------------- causal flash attention (32x32 MFMA, in-register P) --------
// grid (NH, B, 16); block = 4 waves (256 thr); wave w owns q rows
// [jj*128 + 32w, +31], jj = 15 - bz (LPT). K/V double-buffered in LDS (32KB).
// S^T = mfma32(Kfrag, Qfrag); lane owns q-col c31 = lane&31 (pair a=lane>>5).
// O^T = mfma32(V^Tfrag, Pfrag); Pfrag assembled in-register: own cvt-packs +
// partner packs via ds_bpermute(lane^32). Softmax/rescale/epilogue lane-local.
__global__ void __launch_bounds__(256, 4)
attn_fwd(const unsigned short* __restrict__ Qb, const unsigned short* __restrict__ Kb,
         const unsigned short* __restrict__ Vg, unsigned short* __restrict__ Ob)
{
    __shared__ unsigned short Kt[2][64 * 64];  // K tile [s][d], chunk-swizzled
    __shared__ unsigned short Vt[2][64 * 64];  // V^T tile [d][s], chunk-swizzled
    const int tid = threadIdx.x, lane = tid & 63, wv = tid >> 6;
    const int c31 = lane & 31, a = lane >> 5;
    const int h = blockIdx.x, b = blockIdx.y;
    const int jj = 15 - blockIdx.z;            // stripe (LPT: big first)
    const size_t bh = (size_t)b * NH + h;
    const unsigned short* K0 = Kb + bh * SEQ * HD;
    const unsigned short* V0 = Vg + bh * HD * SEQ;
    // staging source offsets (chunk-swizzled), 2 GLDS16 per tensor per thread
    const int li1 = 256 + tid;
    const int kr0 = (tid >> 3) * HD + (((tid & 7) ^ ((tid >> 3) & 7)) << 3);
    const int kr1 = (li1 >> 3) * HD + (((li1 & 7) ^ ((li1 >> 3) & 7)) << 3);
    const int vr0 = (tid >> 3) * SEQ + (((tid & 7) ^ ((tid >> 3) & 7)) << 3);
    const int vr1 = (li1 >> 3) * SEQ + (((li1 & 7) ^ ((li1 >> 3) & 7)) << 3);

    const int qw = jj * 128 + wv * 32;         // wave's first q row
    const int kmax = 2 * jj + 1;               // block-wide last k-tile (64-wide)
    const int sw7 = (c31 & 7);                 // LDS read swizzle key
    const int pidx = (lane ^ 32) << 2;         // bpermute partner index

    // Q B-frags: lane holds Q[qw + c31][dwin*16 + a*8 .. +7]
    const unsigned short* Qp = Qb + (bh * SEQ + qw + c31) * HD + a * 8;
    s16x8 qf[4];
#pragma unroll
    for (int dwin = 0; dwin < 4; ++dwin)
        qf[dwin] = *(const s16x8*)(Qp + dwin * 16);

    f32x16 o[2];                               // O^T accum, two d-halves
#pragma unroll
    for (int r = 0; r < 16; ++r) { o[0][r] = 0.f; o[1][r] = 0.f; }
    float m_run = -INFINITY, l_run = 0.f;

    {   // prologue: stage K/V(0) into buffer 0
        GLDS16(K0 + kr0, &Kt[0][0] + wv * 512);
        GLDS16(K0 + kr1, &Kt[0][2048] + wv * 512);
        GLDS16(V0 + vr0, &Vt[0][0] + wv * 512);
        GLDS16(V0 + vr1, &Vt[0][2048] + wv * 512);
    }

    for (int kt = 0; kt <= kmax; ++kt) {
        __syncthreads();           // publishes buffer kt&1 (drains GLDS)
        const int cur = kt & 1;
        if (kt < kmax) {           // prefetch kt+1 into the other buffer
            const unsigned short* Kg = K0 + (size_t)(kt + 1) * 64 * HD;
            GLDS16(Kg + kr0, &Kt[cur ^ 1][0] + wv * 512);
            GLDS16(Kg + kr1, &Kt[cur ^ 1][2048] + wv * 512);
            const unsigned short* Vp = V0 + (kt + 1) * 64;
            GLDS16(Vp + vr0, &Vt[cur ^ 1][0] + wv * 512);
            GLDS16(Vp + vr1, &Vt[cur ^ 1][2048] + wv * 512);
        }
        if (kt * 64 > qw) continue;   // wave-uniform skip past its diagonal
        const unsigned short* Kc = &Kt[cur][0];
        const unsigned short* Vc = &Vt[cur][0];

#pragma unroll
        for (int ks = 0; ks < 2; ++ks) {
            const int kb = kt * 64 + ks * 32;
            if (kb > qw) break;       // second subtile may be fully masked
            // ---- QK^T: S^T[32k][32q], contraction over d = 4 windows ----
            f32x16 s;
#pragma unroll
            for (int r = 0; r < 16; ++r) s[r] = 0.f;
            __builtin_amdgcn_s_setprio(1);
#pragma unroll
            for (int dwin = 0; dwin < 4; ++dwin) {
                s16x8 kf = *(const s16x8*)(&Kc[(ks * 32 + c31) * 64 +
                                               (((dwin * 2 + a) ^ sw7) << 3)]);
                s = __builtin_amdgcn_mfma_f32_32x32x16_bf16(kf, qf[dwin], s, 0, 0, 0);
            }
            __builtin_amdgcn_s_setprio(0);
            if (kb == qw) {           // diagonal subtile: mask k > q
#pragma unroll
                for (int r = 0; r < 16; ++r) {
                    int kr = (r & 3) + 8 * (r >> 2) + 4 * a;
                    if (kr > c31) s[r] = -INFINITY;
                }
            }
            // ---- online softmax (lane-pair owns column q = c31) ----
            float mloc = s[0];
#pragma unroll
            for (int r = 1; r < 16; ++r) mloc = fmaxf(mloc, s[r]);
            mloc = fmaxf(mloc, __shfl_xor(mloc, 32));
            // defer-max (T13): rescale only when growth exceeds 8 (exp2 dom)
            if (__any(mloc > m_run + 8.0f)) {
                float mnew = fmaxf(m_run, mloc);
                float alpha = __builtin_amdgcn_exp2f(m_run - mnew);
                m_run = mnew;
                l_run *= alpha;
#pragma unroll
                for (int r = 0; r < 16; ++r) { o[0][r] *= alpha; o[1][r] *= alpha; }
            }
            float rs = 0.f;
#pragma unroll
            for (int r = 0; r < 16; ++r) {
                float p = __builtin_amdgcn_exp2f(s[r] - m_run);
                s[r] = p;
                rs += p;
            }
            rs += __shfl_xor(rs, 32);
            l_run += rs;
            // ---- PV: O^T += V^T . P, P-frag assembled in-register ----
#pragma unroll
            for (int win = 0; win < 2; ++win) {
                unsigned int X0 = pkbf(s[8 * win + 0], s[8 * win + 1]);
                unsigned int X1 = pkbf(s[8 * win + 2], s[8 * win + 3]);
                unsigned int Y0 = pkbf(s[8 * win + 4], s[8 * win + 5]);
                unsigned int Y1 = pkbf(s[8 * win + 6], s[8 * win + 7]);
                unsigned int bX0 = (unsigned int)__builtin_amdgcn_ds_bpermute(pidx, (int)X0);
                unsigned int bX1 = (unsigned int)__builtin_amdgcn_ds_bpermute(pidx, (int)X1);
                unsigned int bY0 = (unsigned int)__builtin_amdgcn_ds_bpermute(pidx, (int)Y0);
                unsigned int bY1 = (unsigned int)__builtin_amdgcn_ds_bpermute(pidx, (int)Y1);
                u32x4 pd;
                pd[0] = a ? bY0 : X0;   // k-window offset j = 0,1
                pd[1] = a ? bY1 : X1;   // j = 2,3
                pd[2] = a ? Y0 : bX0;   // j = 4,5
                pd[3] = a ? Y1 : bX1;   // j = 6,7
                s16x8 pf = __builtin_bit_cast(s16x8, pd);
                __builtin_amdgcn_s_setprio(1);
#pragma unroll
                for (int dh = 0; dh < 2; ++dh) {
                    s16x8 vf = *(const s16x8*)(&Vc[(dh * 32 + c31) * 64 +
                                                   (((ks * 4 + win * 2 + a) ^ sw7) << 3)]);
                    o[dh] = __builtin_amdgcn_mfma_f32_32x32x16_bf16(vf, pf, o[dh], 0, 0, 0);
                }
                __builtin_amdgcn_s_setprio(0);
            }
        }
    }
    // epilogue: lane owns q row qw + c31; O^T regs hold d = (r&3)+8*(r>>2)+4a
    float linv = 1.0f / l_run;
    size_t rowbase = ((size_t)b * SEQ + qw + c31) * EMBED + h * HD;
#pragma unroll
    for (int dh = 0; dh < 2; ++dh) {
#pragma unroll
        for (int rq = 0; rq < 4; ++rq) {
            s16x4 pk;
#pragma unroll
            for (int j = 0; j < 4; ++j)
                pk[j] = (short)f2bf(o[dh][rq * 4 + j] * linv);
            *(s16x4*)(&Ob[rowbase + dh * 32 + rq * 8 + a * 4]) = pk;
        }
    }
}

extern "C" void kernel_launch(void* const* d_in, const int* in_sizes, int n_in,
                              void* d_out, int out_size, void* d_ws, size_t ws_size,
                              hipStream_t stream)
{
    (void)in_sizes; (void)n_in; (void)out_size; (void)ws_size;
    const float* Xq = (const float*)d_in[0];
    const float* Xk = (const float*)d_in[1];
    const float* Xv = (const float*)d_in[2];
    // d_in[3] = attn_mask: tril(ones) -> causal handled analytically
    const float* Wq = (const float*)d_in[4];
    const float* bq = (const float*)d_in[5];
    const float* Wk = (const float*)d_in[6];
    const float* bk = (const float*)d_in[7];
    const float* Wv = (const float*)d_in[8];
    const float* bv = (const float*)d_in[9];
    const float* Wo = (const float*)d_in[10];
    const float* bo = (const float*)d_in[11];
    float* Out = (float*)d_out;

    unsigned short* ws = (unsigned short*)d_ws;
    unsigned short* wqb = ws;                    // 4 x 1M elts (weights bf16)
    unsigned short* wkb = wqb + 1048576;
    unsigned short* wvb = wkb + 1048576;
    unsigned short* wob = wvb + 1048576;
    unsigned short* xqb = wob + 1048576;         // 3 x 8M elts (X bf16)
    unsigned short* xkb = xqb + 8388608;
    unsigned short* xvb = xkb + 8388608;
    unsigned short* Qb  = xvb + 8388608;         // [B][H][S][D] bf16
    unsigned short* Kb  = Qb + 8388608;          // [B][H][S][D] bf16
    unsigned short* Vb  = Kb + 8388608;          // [B][H][D][S] bf16 (V^T)
    unsigned short* Ax  = xqb;                   // attn out bf16 [B][S][E]
                                                 // (aliases xqb: dead after gemm_qkv)

    CvtArgs ca;
    ca.s[0] = Wq; ca.s[1] = Wk; ca.s[2] = Wv; ca.s[3] = Wo;
    ca.s[4] = Xq; ca.s[5] = Xk; ca.s[6] = Xv;
    ca.d[0] = wqb; ca.d[1] = wkb; ca.d[2] = wvb; ca.d[3] = wob;
    ca.d[4] = xqb; ca.d[5] = xkb; ca.d[6] = xvb;
    ca.n4[0] = ca.n4[1] = ca.n4[2] = ca.n4[3] = 262144;    // 1024*1024/4
    ca.n4[4] = ca.n4[5] = ca.n4[6] = 2097152;              // 8192*1024/4
    cvt_all<<<dim3(2048, 7), 256, 0, stream>>>(ca);

    ProjArgs pa;
    pa.X[0] = xqb; pa.X[1] = xkb; pa.X[2] = xvb;
    pa.W[0] = wqb; pa.W[1] = wkb; pa.W[2] = wvb;
    pa.Bz[0] = bq; pa.Bz[1] = bk; pa.Bz[2] = bv;
    pa.Oz[0] = Qb; pa.Oz[1] = Kb; pa.Oz[2] = Vb;
    gemm_qkv<<<dim3(64, 8, 3), 256, 0, stream>>>(pa);

    attn_fwd<<<dim3(NH, 4, 16), 256, 0, stream>>>(Qb, Kb, Vb, Ax);

    gemm_out<<<dim3(64, 8), 256, 0, stream>>>(Ax, wob, bo, Out);
}

// Round 9
// 309.757 us; speedup vs baseline: 1.0272x; 1.0272x over previous
//
#include <hip/hip_runtime.h>
#include <math.h>

// MHA forward: B=4, S=2048, E=1024, H=16, D=64. bf16 MFMA path.
// Round 13: attn_fwd = r12's 32x32 in-register-P inner loop + r11's 8-wave
// blocks. 512-thr blocks, 8 waves x 32 q-rows = 256-row stripes, grid
// (NH,4,8) = 512 blocks = 2/CU fully resident (16 waves/CU, 2x r12's
// residency). K/V staged once per 256 q-rows: one GLDS16 per tensor per
// thread (staging insts and K/V HBM refetch halved vs r12). Inner loop,
// softmax, P-frag assembly, epilogue unchanged from r12 (verified layouts).
// gemm/cvt kernels unchanged from round 11.

#define EMBED 1024
#define SEQ   2048
#define NH    16
#define HD    64
#define QSCALE 0.18033688011112042f   // 0.125 * log2(e), folded into Q proj

typedef __attribute__((ext_vector_type(4))) float f32x4;
typedef __attribute__((ext_vector_type(16))) float f32x16;
typedef __attribute__((ext_vector_type(8))) short s16x8;
typedef __attribute__((ext_vector_type(4))) short s16x4;
typedef __attribute__((ext_vector_type(4))) unsigned int u32x4;
typedef __attribute__((ext_vector_type(2))) unsigned int u32x2;

#define GLDS16(gp, lp) __builtin_amdgcn_global_load_lds( \
    (const __attribute__((address_space(1))) void*)(gp), \
    (__attribute__((address_space(3))) void*)(lp), 16, 0, 0)

__device__ __forceinline__ unsigned short f2bf(float f) {   // RNE
    unsigned int u = __builtin_bit_cast(unsigned int, f);
    u += 0x7fffu + ((u >> 16) & 1u);
    return (unsigned short)(u >> 16);
}
// pack two fp32 -> bf16x2 dword by truncation (1 v_perm_b32)
__device__ __forceinline__ unsigned int pkbf(float lo, float hi) {
    return __builtin_amdgcn_perm(__builtin_bit_cast(unsigned int, hi),
                                 __builtin_bit_cast(unsigned int, lo),
                                 0x07060302u);
}

// ---------- fp32 -> bf16 (RNE): 4 weight tensors + 3 activation tensors ----
struct CvtArgs { const float* s[7]; unsigned short* d[7]; int n4[7]; };
__global__ void cvt_all(CvtArgs ca)
{
    const int t = blockIdx.y;
    const float* in = ca.s[t];
    unsigned short* out = ca.d[t];
    const int n4 = ca.n4[t];
    const int stride = gridDim.x * 256;
    for (int i = blockIdx.x * 256 + threadIdx.x; i < n4; i += stride) {
        f32x4 v = *(const f32x4*)(in + (size_t)i * 4);
        s16x4 p;
        p[0] = (short)f2bf(v[0]); p[1] = (short)f2bf(v[1]);
        p[2] = (short)f2bf(v[2]); p[3] = (short)f2bf(v[3]);
        *(s16x4*)(out + (size_t)i * 4) = p;
    }
}

// ---------------- QKV projection (z = 0:Q, 1:K, 2:V), pure bf16 ------------
struct ProjArgs {
    const unsigned short* X[3];
    const unsigned short* W[3];
    const float* Bz[3];
    unsigned short* Oz[3];
};
__global__ void __launch_bounds__(256, 4)
gemm_qkv(ProjArgs pa)
{
    __shared__ unsigned short Ab[128 * 64];    // bf16 X tile (16 KB), swizzled
    __shared__ unsigned short Bb[128 * 64];    // bf16 W tile (16 KB), swizzled
    const int z = blockIdx.z;
    const unsigned short* Xb = pa.X[z];
    const unsigned short* Wb = pa.W[z];
    const float* bias = pa.Bz[z];
    unsigned short* Out = pa.Oz[z];
    const float scale = (z == 0) ? QSCALE : 1.0f;
    const int tid = threadIdx.x, lane = tid & 63, wv = tid >> 6;
    const int g = lane >> 4, c = lane & 15;
    const int wx = wv & 1, wy = wv >> 1;
    const int bm0 = blockIdx.x * 128, bn0 = blockIdx.y * 128;

    f32x4 acc[4][4];
#pragma unroll
    for (int i = 0; i < 4; ++i)
#pragma unroll
        for (int n = 0; n < 4; ++n) acc[i][n] = f32x4{0.f, 0.f, 0.f, 0.f};

    for (int k0 = 0; k0 < EMBED; k0 += 64) {
        __syncthreads();
#pragma unroll
        for (int cc = 0; cc < 4; ++cc) {       // A bf16: 8 chunks/row, swz ^(row&7)
            int li = cc * 256 + tid;
            int row = li >> 3, ch = (li & 7) ^ (row & 7);
            GLDS16(Xb + (size_t)(bm0 + row) * EMBED + k0 + ch * 8,
                   Ab + cc * 2048 + wv * 512);
        }
#pragma unroll
        for (int cc = 0; cc < 4; ++cc) {       // B bf16: 8 chunks/row, swz ^(row&7)
            int li = cc * 256 + tid;
            int row = li >> 3, ch = (li & 7) ^ (row & 7);
            GLDS16(Wb + (size_t)(bn0 + row) * EMBED + k0 + ch * 8,
                   Bb + cc * 2048 + wv * 512);
        }
        __syncthreads();
#pragma unroll
        for (int ks = 0; ks < 2; ++ks) {
            const int ib = ((ks * 4 + g) ^ (c & 7)) * 8;
            s16x8 af[4], bfr[4];
#pragma unroll
            for (int i = 0; i < 4; ++i)
                af[i] = *(const s16x8*)(&Ab[(wy * 64 + i * 16 + c) * 64 + ib]);
#pragma unroll
            for (int n = 0; n < 4; ++n)
                bfr[n] = *(const s16x8*)(&Bb[(wx * 64 + n * 16 + c) * 64 + ib]);
#pragma unroll
            for (int i = 0; i < 4; ++i)
#pragma unroll
                for (int n = 0; n < 4; ++n)
                    acc[i][n] = __builtin_amdgcn_mfma_f32_16x16x32_bf16(af[i], bfr[n], acc[i][n], 0, 0, 0);
        }
    }
    if (z < 2) {        // Q/K -> [B][H][S][D]
#pragma unroll
        for (int i = 0; i < 4; ++i) {
            int m0 = bm0 + wy * 64 + i * 16 + g * 4;
            int bb = m0 >> 11, s0 = m0 & 2047;
#pragma unroll
            for (int n = 0; n < 4; ++n) {
                int ncol = bn0 + wx * 64 + n * 16 + c;
                float bv = bias[ncol];
                int hh = ncol >> 6, dd = ncol & 63;
                size_t base = (((size_t)bb * NH + hh) * SEQ + s0) * HD + dd;
#pragma unroll
                for (int r = 0; r < 4; ++r)
                    Out[base + (size_t)r * HD] = f2bf((acc[i][n][r] + bv) * scale);
            }
        }
    } else {            // V -> V^T [B][H][D][S], 8B stores
#pragma unroll
        for (int i = 0; i < 4; ++i) {
            int m0 = bm0 + wy * 64 + i * 16 + g * 4;
            int bb = m0 >> 11, s0 = m0 & 2047;
#pragma unroll
            for (int n = 0; n < 4; ++n) {
                int ncol = bn0 + wx * 64 + n * 16 + c;
                float bv = bias[ncol];
                int hh = ncol >> 6, dd = ncol & 63;
                s16x4 pk;
#pragma unroll
                for (int r = 0; r < 4; ++r) pk[r] = (short)f2bf(acc[i][n][r] + bv);
                *(s16x4*)(&Out[(((size_t)bb * NH + hh) * HD + dd) * SEQ + s0]) = pk;
            }
        }
    }
}

// ---------------- output projection -----------------------------------------
__global__ void __launch_bounds__(256, 4)
gemm_out(const unsigned short* __restrict__ Xb, const unsigned short* __restrict__ Wb,
         const float* __restrict__ bias, float* __restrict__ Out)
{
    __shared__ unsigned short Ab[128 * 64];
    __shared__ unsigned short Bb[128 * 64];
    const int tid = threadIdx.x;
    const int lane = tid & 63, wv = tid >> 6;
    const int g = lane >> 4, c = lane & 15;
    const int wx = wv & 1, wy = wv >> 1;
    const int bm0 = blockIdx.x * 128, bn0 = blockIdx.y * 128;

    f32x4 acc[4][4];
#pragma unroll
    for (int i = 0; i < 4; ++i)
#pragma unroll
        for (int n = 0; n < 4; ++n) acc[i][n] = f32x4{0.f, 0.f, 0.f, 0.f};

    for (int k0 = 0; k0 < EMBED; k0 += 64) {
        __syncthreads();
#pragma unroll
        for (int cc = 0; cc < 4; ++cc) {
            int li = cc * 256 + tid;
            int row = li >> 3, ch = (li & 7) ^ (row & 7);
            GLDS16(Xb + (size_t)(bm0 + row) * EMBED + k0 + ch * 8,
                   Ab + cc * 2048 + wv * 512);
        }
#pragma unroll
        for (int cc = 0; cc < 4; ++cc) {
            int li = cc * 256 + tid;
            int row = li >> 3, ch = (li & 7) ^ (row & 7);
            GLDS16(Wb + (size_t)(bn0 + row) * EMBED + k0 + ch * 8,
                   Bb + cc * 2048 + wv * 512);
        }
        __syncthreads();
#pragma unroll
        for (int ks = 0; ks < 2; ++ks) {
            const int ib = ((ks * 4 + g) ^ (c & 7)) * 8;
            s16x8 af[4], bfr[4];
#pragma unroll
            for (int i = 0; i < 4; ++i)
                af[i] = *(const s16x8*)(&Ab[(wy * 64 + i * 16 + c) * 64 + ib]);
#pragma unroll
            for (int n = 0; n < 4; ++n)
                bfr[n] = *(const s16x8*)(&Bb[(wx * 64 + n * 16 + c) * 64 + ib]);
#pragma unroll
            for (int i = 0; i < 4; ++i)
#pragma unroll
                for (int n = 0; n < 4; ++n)
                    acc[i][n] = __builtin_amdgcn_mfma_f32_16x16x32_bf16(af[i], bfr[n], acc[i][n], 0, 0, 0);
        }
    }
#pragma unroll
    for (int i = 0; i < 4; ++i) {
#pragma unroll
        for (int n = 0; n < 4; ++n) {
            int ncol = bn0 + wx * 64 + n * 16 + c;
            float bv = bias[ncol];
#pragma unroll
            for (int r = 0; r < 4; ++r) {
                int m = bm0 + wy * 64 + i * 16 + g * 4 + r;
                Out[(size_t)m * EMBED + ncol] = acc[i][n][r] + bv;
            }
        }
    }
}

// ---------------- causal flash attention (32x32 MFMA, 8-wave blocks) --------
// grid (NH, B, 8); block = 8 waves (512 thr); wave w owns q rows
// [jj*256 + 32w, +31], jj = 7 - bz (LPT). K/V double-buffered in LDS (32KB),
// staged once per 256 q-rows: one GLDS16 per tensor per thread.
// S^T = mfma32(Kfrag, Qfrag); lane owns q-col c31 = lane&31 (pair a=lane>>5).
// O^T = mfma32(V^Tfrag, Pfrag); Pfrag assembled in-register: own cvt-packs +
// partner packs via ds_bpermute(lane^32). Softmax/rescale/epilogue lane-local.
__global__ void __launch_bounds__(512, 4)
attn_fwd(const unsigned short* __restrict__ Qb, const unsigned short* __restrict__ Kb,
         const unsigned short* __restrict__ Vg, unsigned short* __restrict__ Ob)
{
    __shared__ unsigned short Kt[2][64 * 64];  // K tile [s][d], chunk-swizzled
    __shared__ unsigned short Vt[2][64 * 64];  // V^T tile [d][s], chunk-swizzled
    const int tid = threadIdx.x, lane = tid & 63, wv = tid >> 6;
    const int c31 = lane & 31, a = lane >> 5;
    const int h = blockIdx.x, b = blockIdx.y;
    const int jj = 7 - blockIdx.z;             // stripe (LPT: big first)
    const size_t bh = (size_t)b * NH + h;
    const unsigned short* K0 = Kb + bh * SEQ * HD;
    const unsigned short* V0 = Vg + bh * HD * SEQ;
    // staging: 512 threads cover 64 rows x 8 chunks (one GLDS16 per tensor)
    const int srow = tid >> 3;
    const int sch = (tid & 7) ^ (srow & 7);    // self-inverse chunk swizzle
    const int kr = srow * HD + sch * 8;
    const int vr = srow * SEQ + sch * 8;

    const int qw = jj * 256 + wv * 32;         // wave's first q row
    const int kmax = 4 * jj + 3;               // block-wide last k-tile (64-wide)
    const int sw7 = (c31 & 7);                 // LDS read swizzle key
    const int pidx = (lane ^ 32) << 2;         // bpermute partner index

    // Q B-frags: lane holds Q[qw + c31][dwin*16 + a*8 .. +7]
    const unsigned short* Qp = Qb + (bh * SEQ + qw + c31) * HD + a * 8;
    s16x8 qf[4];
#pragma unroll
    for (int dwin = 0; dwin < 4; ++dwin)
        qf[dwin] = *(const s16x8*)(Qp + dwin * 16);

    f32x16 o[2];                               // O^T accum, two d-halves
#pragma unroll
    for (int r = 0; r < 16; ++r) { o[0][r] = 0.f; o[1][r] = 0.f; }
    float m_run = -INFINITY, l_run = 0.f;

    {   // prologue: stage K/V(0) into buffer 0
        GLDS16(K0 + kr, &Kt[0][0] + wv * 512);
        GLDS16(V0 + vr, &Vt[0][0] + wv * 512);
    }

    for (int kt = 0; kt <= kmax; ++kt) {
        __syncthreads();           // publishes buffer kt&1 (drains GLDS)
        const int cur = kt & 1;
        if (kt < kmax) {           // prefetch kt+1 into the other buffer
            GLDS16(K0 + (size_t)(kt + 1) * 64 * HD + kr, &Kt[cur ^ 1][0] + wv * 512);
            GLDS16(V0 + (kt + 1) * 64 + vr, &Vt[cur ^ 1][0] + wv * 512);
        }
        if (kt * 64 > qw) continue;   // wave-uniform skip past its diagonal
        const unsigned short* Kc = &Kt[cur][0];
        const unsigned short* Vc = &Vt[cur][0];

#pragma unroll
        for (int ks = 0; ks < 2; ++ks) {
            const int kb = kt * 64 + ks * 32;
            if (kb > qw) break;       // second subtile may be fully masked
            // ---- QK^T: S^T[32k][32q], contraction over d = 4 windows ----
            f32x16 s;
#pragma unroll
            for (int r = 0; r < 16; ++r) s[r] = 0.f;
            __builtin_amdgcn_s_setprio(1);
#pragma unroll
            for (int dwin = 0; dwin < 4; ++dwin) {
                s16x8 kf = *(const s16x8*)(&Kc[(ks * 32 + c31) * 64 +
                                               (((dwin * 2 + a) ^ sw7) << 3)]);
                s = __builtin_amdgcn_mfma_f32_32x32x16_bf16(kf, qf[dwin], s, 0, 0, 0);
            }
            __builtin_amdgcn_s_setprio(0);
            if (kb == qw) {           // diagonal subtile: mask k > q
#pragma unroll
                for (int r = 0; r < 16; ++r) {
                    int kr_ = (r & 3) + 8 * (r >> 2) + 4 * a;
                    if (kr_ > c31) s[r] = -INFINITY;
                }
            }
            // ---- online softmax (lane-pair owns column q = c31) ----
            float mloc = s[0];
#pragma unroll
            for (int r = 1; r < 16; ++r) mloc = fmaxf(mloc, s[r]);
            mloc = fmaxf(mloc, __shfl_xor(mloc, 32));
            // defer-max (T13): rescale only when growth exceeds 8 (exp2 dom)
            if (__any(mloc > m_run + 8.0f)) {
                float mnew = fmaxf(m_run, mloc);
                float alpha = __builtin_amdgcn_exp2f(m_run - mnew);
                m_run = mnew;
                l_run *= alpha;
#pragma unroll
                for (int r = 0; r < 16; ++r) { o[0][r] *= alpha; o[1][r] *= alpha; }
            }
            float rs = 0.f;
#pragma unroll
            for (int r = 0; r < 16; ++r) {
                float p = __builtin_amdgcn_exp2f(s[r] - m_run);
                s[r] = p;
                rs += p;
            }
            rs += __shfl_xor(rs, 32);
            l_run += rs;
            // ---- PV: O^T += V^T . P, P-frag assembled in-register ----
#pragma unroll
            for (int win = 0; win < 2; ++win) {
                unsigned int X0 = pkbf(s[8 * win + 0], s[8 * win + 1]);
                unsigned int X1 = pkbf(s[8 * win + 2], s[8 * win + 3]);
                unsigned int Y0 = pkbf(s[8 * win + 4], s[8 * win + 5]);
                unsigned int Y1 = pkbf(s[8 * win + 6], s[8 * win + 7]);
                unsigned int bX0 = (unsigned int)__builtin_amdgcn_ds_bpermute(pidx, (int)X0);
                unsigned int bX1 = (unsigned int)__builtin_amdgcn_ds_bpermute(pidx, (int)X1);
                unsigned int bY0 = (unsigned int)__builtin_amdgcn_ds_bpermute(pidx, (int)Y0);
                unsigned int bY1 = (unsigned int)__builtin_amdgcn_ds_bpermute(pidx, (int)Y1);
                u32x4 pd;
                pd[0] = a ? bY0 : X0;   // k-window offset j = 0,1
                pd[1] = a ? bY1 : X1;   // j = 2,3
                pd[2] = a ? Y0 : bX0;   // j = 4,5
                pd[3] = a ? Y1 : bX1;   // j = 6,7
                s16x8 pf = __builtin_bit_cast(s16x8, pd);
                __builtin_amdgcn_s_setprio(1);
#pragma unroll
                for (int dh = 0; dh < 2; ++dh) {
                    s16x8 vf = *(const s16x8*)(&Vc[(dh * 32 + c31) * 64 +
                                                   (((ks * 4 + win * 2 + a) ^ sw7) << 3)]);
                    o[dh] = __builtin_amdgcn_mfma_f32_32x32x16_bf16(vf, pf, o[dh], 0, 0, 0);
                }
                __builtin_amdgcn_s_setprio(0);
            }
        }
    }
    // epilogue: lane owns q row qw + c31; O^T regs hold d = (r&3)+8*(r>>2)+4a
    float linv = 1.0f / l_run;
    size_t rowbase = ((size_t)b * SEQ + qw + c31) * EMBED + h * HD;
#pragma unroll
    for (int dh = 0; dh < 2; ++dh) {
#pragma unroll
        for (int rq = 0; rq < 4; ++rq) {
            s16x4 pk;
#pragma unroll
            for (int j = 0; j < 4; ++j)
                pk[j] = (short)f2bf(o[dh][rq * 4 + j] * linv);
            *(s16x4*)(&Ob[rowbase + dh * 32 + rq * 8 + a * 4]) = pk;
        }
    }
}

extern "C" void kernel_launch(void* const* d_in, const int* in_sizes, int n_in,
                              void* d_out, int out_size, void* d_ws, size_t ws_size,
                              hipStream_t stream)
{
    (void)in_sizes; (void)n_in; (void)out_size; (void)ws_size;
    const float* Xq = (const float*)d_in[0];
    const float* Xk = (const float*)d_in[1];
    const float* Xv = (const float*)d_in[2];
    // d_in[3] = attn_mask: tril(ones) -> causal handled analytically
    const float* Wq = (const float*)d_in[4];
    const float* bq = (const float*)d_in[5];
    const float* Wk = (const float*)d_in[6];
    const float* bk = (const float*)d_in[7];
    const float* Wv = (const float*)d_in[8];
    const float* bv = (const float*)d_in[9];
    const float* Wo = (const float*)d_in[10];
    const float* bo = (const float*)d_in[11];
    float* Out = (float*)d_out;

    unsigned short* ws = (unsigned short*)d_ws;
    unsigned short* wqb = ws;                    // 4 x 1M elts (weights bf16)
    unsigned short* wkb = wqb + 1048576;
    unsigned short* wvb = wkb + 1048576;
    unsigned short* wob = wvb + 1048576;
    unsigned short* xqb = wob + 1048576;         // 3 x 8M elts (X bf16)
    unsigned short* xkb = xqb + 8388608;
    unsigned short* xvb = xkb + 8388608;
    unsigned short* Qb  = xvb + 8388608;         // [B][H][S][D] bf16
    unsigned short* Kb  = Qb + 8388608;          // [B][H][S][D] bf16
    unsigned short* Vb  = Kb + 8388608;          // [B][H][D][S] bf16 (V^T)
    unsigned short* Ax  = xqb;                   // attn out bf16 [B][S][E]
                                                 // (aliases xqb: dead after gemm_qkv)

    CvtArgs ca;
    ca.s[0] = Wq; ca.s[1] = Wk; ca.s[2] = Wv; ca.s[3] = Wo;
    ca.s[4] = Xq; ca.s[5] = Xk; ca.s[6] = Xv;
    ca.d[0] = wqb; ca.d[1] = wkb; ca.d[2] = wvb; ca.d[3] = wob;
    ca.d[4] = xqb; ca.d[5] = xkb; ca.d[6] = xvb;
    ca.n4[0] = ca.n4[1] = ca.n4[2] = ca.n4[3] = 262144;    // 1024*1024/4
    ca.n4[4] = ca.n4[5] = ca.n4[6] = 2097152;              // 8192*1024/4
    cvt_all<<<dim3(2048, 7), 256, 0, stream>>>(ca);

    ProjArgs pa;
    pa.X[0] = xqb; pa.X[1] = xkb; pa.X[2] = xvb;
    pa.W[0] = wqb; pa.W[1] = wkb; pa.W[2] = wvb;
    pa.Bz[0] = bq; pa.Bz[1] = bk; pa.Bz[2] = bv;
    pa.Oz[0] = Qb; pa.Oz[1] = Kb; pa.Oz[2] = Vb;
    gemm_qkv<<<dim3(64, 8, 3), 256, 0, stream>>>(pa);

    attn_fwd<<<dim3(NH, 4, 8), 512, 0, stream>>>(Qb, Kb, Vb, Ax);

    gemm_out<<<dim3(64, 8), 256, 0, stream>>>(Ax, wob, bo, Out);
}